// Round 8
// baseline (117.741 us; speedup 1.0000x reference)
//
#include <hip/hip_runtime.h>
#include <hip/hip_fp16.h>

#define HH 512
#define WW 512
#define TS 32
#define SQH 42
#define SQW 42
#define O1H 39
#define O1W 39
#define O2H 35
#define O2W 35

// d_ws float layout (all weights pre-transposed/pre-folded by prep kernel):
#define W2T 0     /* [tap9][ci3][c4]   108 */
#define W3T 108   /* [tap4][ci7][c8]   224 (o2cat sq-chans folded) */
#define W4T 332   /* [u15][c16]        240 (dup cat-chans folded)  */
#define B2O 572
#define B3O 576
#define B4O 584

__global__ void prep_weights(const float* __restrict__ w2, const float* __restrict__ b2,
                             const float* __restrict__ w3, const float* __restrict__ b3,
                             const float* __restrict__ w4, const float* __restrict__ b4,
                             float* __restrict__ ws)
{
    int t = threadIdx.x;
    if (t < 108) {
        int c = t & 3, ci = (t >> 2) % 3, tap = t / 12;
        int i = tap / 3, j = tap % 3;
        ws[W2T + t] = w2[((c*3+ci)*3+i)*3+j];
    }
    if (t < 224) {
        int c = t & 7, ci = (t >> 3) % 7, tap = t / 56;
        int i = tap >> 1, j = tap & 1;
        float v = w3[((c*8+ci)*2+i)*2+j];
        if (ci == 6) v += w3[((c*8+7)*2+i)*2+j];   // o2cat ch6,7 both = sq
        ws[W3T + t] = v;
    }
    if (t < 240) {
        int c = t & 15, u = t >> 4;
        float v;
        if (u < 12)       v = w4[c*20+u];
        else if (u == 12) v = w4[c*20+12] + w4[c*20+16];
        else if (u == 13) v = w4[c*20+13] + w4[c*20+17];
        else              v = w4[c*20+14] + w4[c*20+15] + w4[c*20+18] + w4[c*20+19];
        ws[W4T + t] = v;
    }
    if (t < 4)  ws[B2O + t] = b2[t];
    if (t < 8)  ws[B3O + t] = b3[t];
    if (t < 16) ws[B4O + t] = b4[t];
}

__global__ __launch_bounds__(256) void enc_fused(
    const float* __restrict__ f,
    const float* __restrict__ w1, const float* __restrict__ b1,
    const float* __restrict__ wf,   // folded weights in d_ws
    float* __restrict__ out)
{
    // fp16 intermediates: LDS 38.8KB -> 22.9KB (6 blocks/CU LDS-wise)
    __shared__ __align__(16) float   s_sq[SQH*SQW];
    __shared__ __align__(16) __half2 s_o1h[O1H*O1W];     // {c0,c1}
    __shared__ __align__(16) __half2 s_o2h[O2H*O2W*2];   // {c0,c1},{c2,c3}

    const int tid = threadIdx.x;
    const int b  = blockIdx.z;
    const int h0 = blockIdx.y * TS;
    const int w0 = blockIdx.x * TS;

    // ---- phase 1: sq = wrapped vertical diff, squared (floor-mod == jnp.mod) ----
    const float* fb = f + (size_t)b * (HH*WW);
    const float PI = 3.14159265358979323846f;
    const float TWO_PI = 6.283185307179586477f;
    const float INV2PI = 0.15915494309189533577f;
    #pragma unroll
    for (int p = 0; p < 7; ++p) {
        int idx = tid + 256*p;
        if (idx < SQH*SQW) {
            int rh = idx / SQW, rwp = idx % SQW;
            int gh = h0 + rh - 4, gw = w0 + rwp - 4;
            float v = 0.f;
            if (gh > 0 && gh < HH && gw >= 0 && gw < WW) {
                float d = fb[gh*WW + gw] - fb[(gh-1)*WW + gw];
                float dd = fmaf(-TWO_PI, floorf((d + PI) * INV2PI), d); // mod(d+pi,2pi)-pi
                if (dd == -PI && d > 0.f) dd = PI;
                float r = (fabsf(d) < PI) ? d : dd;
                v = r * r;
            }
            s_sq[idx] = v;
        }
    }
    __syncthreads();

    // ---- phase 2: o1 4x4 dil1 (pad l1/r2), 1ch -> 2ch; OOB -> 0; fp16 pack ----
    #pragma unroll
    for (int p = 0; p < 6; ++p) {
        int idx = tid + 256*p;
        if (idx < O1H*O1W) {
            int rh = idx / O1W, rwp = idx % O1W;
            float a0 = b1[0], a1 = b1[1];
            #pragma unroll
            for (int i = 0; i < 4; ++i)
            #pragma unroll
            for (int j = 0; j < 4; ++j) {
                float x = s_sq[(rh+i)*SQW + rwp+j];
                a0 += x * w1[i*4+j];
                a1 += x * w1[16+i*4+j];
            }
            int gy = h0 + rh - 3, gx = w0 + rwp - 3;
            bool inimg = (gy >= 0) & (gy < HH) & (gx >= 0) & (gx < WW);
            s_o1h[idx] = __floats2half2_rn(inimg ? a0 : 0.f, inimg ? a1 : 0.f);
        }
    }
    __syncthreads();

    // ---- phase 3: o2 3x3 dil2 (pad 2/2), 3ch -> 4ch; OOB -> 0; fp16 pack ----
    {
        int rh[5], rwp[5]; bool val[5], img[5];
        float acc[4][5];
        #pragma unroll
        for (int p = 0; p < 5; ++p) {
            int idx = tid + 256*p;
            val[p] = idx < O2H*O2W;
            int id = val[p] ? idx : 0;
            rh[p] = id / O2W; rwp[p] = id % O2W;
            int gy = h0 + rh[p] - 1, gx = w0 + rwp[p] - 1;
            img[p] = (gy >= 0) & (gy < HH) & (gx >= 0) & (gx < WW);
            #pragma unroll
            for (int c = 0; c < 4; ++c) acc[c][p] = wf[B2O + c];
        }
        #pragma unroll
        for (int i = 0; i < 3; ++i)
        #pragma unroll
        for (int j = 0; j < 3; ++j) {
            const float4 wa = *(const float4*)&wf[W2T + (i*3+j)*12];
            const float4 wb = *(const float4*)&wf[W2T + (i*3+j)*12 + 4];
            const float4 wc = *(const float4*)&wf[W2T + (i*3+j)*12 + 8];
            #pragma unroll
            for (int p = 0; p < 5; ++p) {
                float2 xo = __half22float2(s_o1h[(rh[p]+2*i)*O1W + rwp[p]+2*j]);
                float  xs = s_sq[(rh[p]+1+2*i)*SQW + rwp[p]+1+2*j];
                acc[0][p] += xo.x*wa.x + xo.y*wb.x + xs*wc.x;
                acc[1][p] += xo.x*wa.y + xo.y*wb.y + xs*wc.y;
                acc[2][p] += xo.x*wa.z + xo.y*wb.z + xs*wc.z;
                acc[3][p] += xo.x*wa.w + xo.y*wb.w + xs*wc.w;
            }
        }
        #pragma unroll
        for (int p = 0; p < 5; ++p) if (val[p]) {
            float x0 = img[p] ? acc[0][p] : 0.f;
            float x1 = img[p] ? acc[1][p] : 0.f;
            float x2 = img[p] ? acc[2][p] : 0.f;
            float x3 = img[p] ? acc[3][p] : 0.f;
            int px = rh[p]*O2W + rwp[p];
            s_o2h[px*2]   = __floats2half2_rn(x0, x1);
            s_o2h[px*2+1] = __floats2half2_rn(x2, x3);
        }
    }
    __syncthreads();

    // ---- stage 3 in two independent halves (2 output rows each) to cap VGPRs ----
    const int rw = tid & 31;
    const int q  = tid >> 5;
    const size_t HWp = (size_t)HH*WW;
    float* ob = out + (size_t)b*48*HWp;

    #pragma unroll 1
    for (int hk = 0; hk < 2; ++hk) {
        const int r0 = q + 16*hk;           // rows r0, r0+8
        int pofs[2];
        #pragma unroll
        for (int kk = 0; kk < 2; ++kk) pofs[kk] = (h0 + r0 + 8*kk)*WW + (w0 + rw);

        // center values
        float sqv[2], o1v[2][2], o2v[4][2];
        #pragma unroll
        for (int kk = 0; kk < 2; ++kk) {
            int rh = r0 + 8*kk;
            sqv[kk] = s_sq[(rh+4)*SQW + rw+4];
            float2 t2 = __half22float2(s_o1h[(rh+3)*O1W + rw+3]);
            o1v[0][kk]=t2.x; o1v[1][kk]=t2.y;
            int px = (rh+1)*O2W + rw+1;
            float2 ab = __half22float2(s_o2h[px*2]);
            float2 cd = __half22float2(s_o2h[px*2+1]);
            o2v[0][kk]=ab.x; o2v[1][kk]=ab.y; o2v[2][kk]=cd.x; o2v[3][kk]=cd.y;
        }

        // early stores: ch24-47 (ascending address order)
        #pragma unroll
        for (int kk = 0; kk < 2; ++kk) {
            float* o = ob + pofs[kk];
            o[24*HWp]=o2v[0][kk]; o[25*HWp]=o2v[1][kk]; o[26*HWp]=o2v[2][kk]; o[27*HWp]=o2v[3][kk];
            o[28*HWp]=o1v[0][kk]; o[29*HWp]=o1v[1][kk]; o[30*HWp]=sqv[kk];    o[31*HWp]=sqv[kk];
            o[32*HWp]=o1v[0][kk]; o[33*HWp]=o1v[1][kk]; o[34*HWp]=sqv[kk];    o[35*HWp]=sqv[kk];
            o[36*HWp]=o2v[0][kk]; o[37*HWp]=o2v[1][kk]; o[38*HWp]=o2v[2][kk]; o[39*HWp]=o2v[3][kk];
            o[40*HWp]=o1v[0][kk]; o[41*HWp]=o1v[1][kk]; o[42*HWp]=sqv[kk];    o[43*HWp]=sqv[kk];
            o[44*HWp]=o1v[0][kk]; o[45*HWp]=o1v[1][kk]; o[46*HWp]=sqv[kk];    o[47*HWp]=sqv[kk];
        }

        // o3: 2x2 dil3 (pad 1/2), 7 unique ci -> 8 co
        float o3v[8][2];
        #pragma unroll
        for (int c = 0; c < 8; ++c) {
            float bv = wf[B3O + c];
            o3v[c][0] = bv; o3v[c][1] = bv;
        }
        #pragma unroll
        for (int i = 0; i < 2; ++i)
        #pragma unroll
        for (int j = 0; j < 2; ++j) {
            float xin[7][2];
            #pragma unroll
            for (int kk = 0; kk < 2; ++kk) {
                int hh = r0 + 8*kk + 3*i, ww2 = rw + 3*j;
                int px = hh*O2W + ww2;
                float2 ab = __half22float2(s_o2h[px*2]);
                float2 cd = __half22float2(s_o2h[px*2+1]);
                xin[0][kk]=ab.x; xin[1][kk]=ab.y; xin[2][kk]=cd.x; xin[3][kk]=cd.y;
                float2 bq = __half22float2(s_o1h[(hh+2)*O1W + ww2+2]);
                xin[4][kk]=bq.x; xin[5][kk]=bq.y;
                xin[6][kk]=s_sq[(hh+3)*SQW + ww2+3];
            }
            #pragma unroll
            for (int ci = 0; ci < 7; ++ci) {
                float4 wa = *(const float4*)&wf[W3T + (i*2+j)*56 + ci*8];
                float4 wb = *(const float4*)&wf[W3T + (i*2+j)*56 + ci*8 + 4];
                #pragma unroll
                for (int kk = 0; kk < 2; ++kk) {
                    float x = xin[ci][kk];
                    o3v[0][kk] += x*wa.x; o3v[1][kk] += x*wa.y;
                    o3v[2][kk] += x*wa.z; o3v[3][kk] += x*wa.w;
                    o3v[4][kk] += x*wb.x; o3v[5][kk] += x*wb.y;
                    o3v[6][kk] += x*wb.z; o3v[7][kk] += x*wb.w;
                }
            }
        }
        #pragma unroll
        for (int kk = 0; kk < 2; ++kk) {
            float* o = ob + pofs[kk];
            #pragma unroll
            for (int c = 0; c < 8; ++c) o[(size_t)(16+c)*HWp] = o3v[c][kk];
        }

        // o4: 1x1, 15 unique inputs -> 16 co
        #pragma unroll
        for (int cg = 0; cg < 4; ++cg) {
            float acc[4][2];
            #pragma unroll
            for (int c = 0; c < 4; ++c) {
                float bv = wf[B4O + cg*4 + c];
                acc[c][0] = bv; acc[c][1] = bv;
            }
            #pragma unroll
            for (int u = 0; u < 15; ++u) {
                float4 wv = *(const float4*)&wf[W4T + u*16 + cg*4];
                #pragma unroll
                for (int kk = 0; kk < 2; ++kk) {
                    float x = (u<8) ? o3v[u][kk] : (u<12) ? o2v[u-8][kk]
                            : (u<14) ? o1v[u-12][kk] : sqv[kk];
                    acc[0][kk]+=x*wv.x; acc[1][kk]+=x*wv.y;
                    acc[2][kk]+=x*wv.z; acc[3][kk]+=x*wv.w;
                }
            }
            #pragma unroll
            for (int c = 0; c < 4; ++c)
            #pragma unroll
            for (int kk = 0; kk < 2; ++kk)
                ob[(size_t)(cg*4+c)*HWp + pofs[kk]] = acc[c][kk];
        }
    }
}

extern "C" void kernel_launch(void* const* d_in, const int* in_sizes, int n_in,
                              void* d_out, int out_size, void* d_ws, size_t ws_size,
                              hipStream_t stream) {
    const float* f  = (const float*)d_in[0];
    const float* w1 = (const float*)d_in[1];
    const float* b1 = (const float*)d_in[2];
    const float* w2 = (const float*)d_in[3];
    const float* b2 = (const float*)d_in[4];
    const float* w3 = (const float*)d_in[5];
    const float* b3 = (const float*)d_in[6];
    const float* w4 = (const float*)d_in[7];
    const float* b4 = (const float*)d_in[8];
    float* out = (float*)d_out;
    float* ws  = (float*)d_ws;

    prep_weights<<<1, 256, 0, stream>>>(w2, b2, w3, b3, w4, b4, ws);
    dim3 grid(WW/TS, HH/TS, 8);
    enc_fused<<<grid, 256, 0, stream>>>(f, w1, b1, ws, out);
}